// Round 2
// baseline (679.649 us; speedup 1.0000x reference)
//
#include <hip/hip_runtime.h>

typedef float v4f __attribute__((ext_vector_type(4)));

#define N_NODES 50000
#define N_ROWS  800000
#define C 128

// ---------------------------------------------------------------------------
// Pass A: W1f = W1[0:128,:] + W1[128:256,:]  (concat([g,g]) @ W1 == g @ W1f)
//         + zero the per-node histogram counters.
// grid 196 blocks x 256 covers both 16384 and 50000.
// ---------------------------------------------------------------------------
__global__ __launch_bounds__(256) void prep_kernel(const float* __restrict__ W1,
                                                   float* __restrict__ W1f,
                                                   int* __restrict__ count) {
    int i = blockIdx.x * 256 + threadIdx.x;
    if (i < C * C) W1f[i] = W1[i] + W1[C * C + i];
    if (i < N_NODES) count[i] = 0;
}

// Pass B: histogram of idx (how many output rows per node)
__global__ __launch_bounds__(256) void hist_kernel(const int* __restrict__ idx,
                                                   int* __restrict__ count) {
    int e = blockIdx.x * 256 + threadIdx.x;
    if (e < N_ROWS) atomicAdd(&count[idx[e]], 1);
}

// Pass C: exclusive scan of counts -> off[0..N_NODES], cursor copy.
// Single block, 1024 threads, 49 elements/thread serial + Hillis-Steele.
__global__ __launch_bounds__(1024) void scan_kernel(const int* __restrict__ count,
                                                    int* __restrict__ off,
                                                    int* __restrict__ cursor) {
    __shared__ int part[1024];
    const int T = 1024;
    const int CHUNK = (N_NODES + T - 1) / T;   // 49
    int t = threadIdx.x;
    int lo = t * CHUNK;
    int hi = lo + CHUNK; if (hi > N_NODES) hi = N_NODES;
    int s = 0;
    for (int i = lo; i < hi; ++i) s += count[i];
    part[t] = s;
    __syncthreads();
    // inclusive scan (read-before-write each round is barrier-separated)
    for (int d = 1; d < T; d <<= 1) {
        int v = (t >= d) ? part[t - d] : 0;
        __syncthreads();
        part[t] += v;
        __syncthreads();
    }
    int run = part[t] - s;                     // exclusive prefix of this chunk
    for (int i = lo; i < hi; ++i) {
        off[i] = run; cursor[i] = run;
        run += count[i];
    }
    if (t == T - 1) off[N_NODES] = run;        // == N_ROWS
}

// Pass D: counting-sort scatter-build. rowlist[pos] = (e<<6) | (node & 63).
// Order within a node's segment is irrelevant (each e writes only its own row).
__global__ __launch_bounds__(256) void build_kernel(const int* __restrict__ idx,
                                                    int* __restrict__ cursor,
                                                    unsigned* __restrict__ rowlist) {
    int e = blockIdx.x * 256 + threadIdx.x;
    if (e < N_ROWS) {
        int n = idx[e];
        int pos = atomicAdd(&cursor[n], 1);
        rowlist[pos] = ((unsigned)e << 6) | (unsigned)(n & 63);
    }
}

// ---------------------------------------------------------------------------
// Pass E (fused): per 64-node tile compute z = relu(x@W1f+b1)@W2+b2 in LDS,
// then scatter each finished row directly to every y position that references
// it (CSR segment [off[node0], off[node0+64))). z never touches global memory:
// saves 25.6 MB z write + 410 MB scattered L3 re-read vs the 2-pass version.
// Block = 256 threads, tile = 64 rows x 128 cols. Thread (rg,cg) computes
// rows {rg,+16,+32,+48} x cols [8cg, 8cg+8). LDS [64][132] (pad => conflict-
// free column reads) reused x-tile -> h-tile -> z-tile, barrier-separated.
// ---------------------------------------------------------------------------
__global__ __launch_bounds__(256) void node_scatter_kernel(
    const float* __restrict__ x, const float* __restrict__ W1f,
    const float* __restrict__ b1, const float* __restrict__ W2,
    const float* __restrict__ b2, const int* __restrict__ off,
    const unsigned* __restrict__ rowlist, v4f* __restrict__ y4)
{
    __shared__ float smem[64 * 132];
    const int tid = threadIdx.x;
    const int cg  = tid & 15;
    const int rg  = tid >> 4;
    const int c0  = cg * 8;
    const int node0 = blockIdx.x * 64;

    // stage x tile (coalesced float4, non-temporal: x is read exactly once)
    {
        int r  = tid >> 5;            // 0..7
        int c4 = (tid & 31) * 4;      // 0..124
        #pragma unroll
        for (int it = 0; it < 8; ++it, r += 8) {
            int gr = node0 + r;
            if (gr >= N_NODES) gr = N_NODES - 1;   // clamp: safe read, never scattered
            v4f v = __builtin_nontemporal_load(
                reinterpret_cast<const v4f*>(&x[(long)gr * C + c4]));
            *reinterpret_cast<v4f*>(&smem[r * 132 + c4]) = v;
        }
    }
    __syncthreads();

    float acc[4][8];
    #pragma unroll
    for (int m = 0; m < 4; ++m)
        #pragma unroll
        for (int j = 0; j < 8; ++j) acc[m][j] = 0.f;

    // GEMM1: h = x @ W1f
    #pragma unroll 4
    for (int k = 0; k < C; ++k) {
        v4f w0 = *reinterpret_cast<const v4f*>(&W1f[k * C + c0]);
        v4f w1 = *reinterpret_cast<const v4f*>(&W1f[k * C + c0 + 4]);
        #pragma unroll
        for (int m = 0; m < 4; ++m) {
            float xv = smem[(rg + 16 * m) * 132 + k];
            acc[m][0] += xv * w0.x; acc[m][1] += xv * w0.y;
            acc[m][2] += xv * w0.z; acc[m][3] += xv * w0.w;
            acc[m][4] += xv * w1.x; acc[m][5] += xv * w1.y;
            acc[m][6] += xv * w1.z; acc[m][7] += xv * w1.w;
        }
    }

    float bb[8];
    #pragma unroll
    for (int j = 0; j < 8; ++j) bb[j] = b1[c0 + j];

    __syncthreads();   // all x reads complete before overwriting buffer with h
    #pragma unroll
    for (int m = 0; m < 4; ++m) {
        int r = rg + 16 * m;
        v4f h0, h1;
        h0.x = acc[m][0] + bb[0]; h0.y = acc[m][1] + bb[1];
        h0.z = acc[m][2] + bb[2]; h0.w = acc[m][3] + bb[3];
        h1.x = acc[m][4] + bb[4]; h1.y = acc[m][5] + bb[5];
        h1.z = acc[m][6] + bb[6]; h1.w = acc[m][7] + bb[7];
        h0.x = h0.x > 0.f ? h0.x : 0.f; h0.y = h0.y > 0.f ? h0.y : 0.f;
        h0.z = h0.z > 0.f ? h0.z : 0.f; h0.w = h0.w > 0.f ? h0.w : 0.f;
        h1.x = h1.x > 0.f ? h1.x : 0.f; h1.y = h1.y > 0.f ? h1.y : 0.f;
        h1.z = h1.z > 0.f ? h1.z : 0.f; h1.w = h1.w > 0.f ? h1.w : 0.f;
        *reinterpret_cast<v4f*>(&smem[r * 132 + c0])     = h0;
        *reinterpret_cast<v4f*>(&smem[r * 132 + c0 + 4]) = h1;
    }
    __syncthreads();

    #pragma unroll
    for (int m = 0; m < 4; ++m)
        #pragma unroll
        for (int j = 0; j < 8; ++j) acc[m][j] = 0.f;

    // GEMM2: z = h @ W2
    #pragma unroll 4
    for (int k = 0; k < C; ++k) {
        v4f w0 = *reinterpret_cast<const v4f*>(&W2[k * C + c0]);
        v4f w1 = *reinterpret_cast<const v4f*>(&W2[k * C + c0 + 4]);
        #pragma unroll
        for (int m = 0; m < 4; ++m) {
            float hv = smem[(rg + 16 * m) * 132 + k];
            acc[m][0] += hv * w0.x; acc[m][1] += hv * w0.y;
            acc[m][2] += hv * w0.z; acc[m][3] += hv * w0.w;
            acc[m][4] += hv * w1.x; acc[m][5] += hv * w1.y;
            acc[m][6] += hv * w1.z; acc[m][7] += hv * w1.w;
        }
    }

    #pragma unroll
    for (int j = 0; j < 8; ++j) bb[j] = b2[c0 + j];

    __syncthreads();   // all h reads complete before overwriting buffer with z
    #pragma unroll
    for (int m = 0; m < 4; ++m) {
        int r = rg + 16 * m;
        v4f o0, o1;
        o0.x = acc[m][0] + bb[0]; o0.y = acc[m][1] + bb[1];
        o0.z = acc[m][2] + bb[2]; o0.w = acc[m][3] + bb[3];
        o1.x = acc[m][4] + bb[4]; o1.y = acc[m][5] + bb[5];
        o1.z = acc[m][6] + bb[6]; o1.w = acc[m][7] + bb[7];
        *reinterpret_cast<v4f*>(&smem[r * 132 + c0])     = o0;
        *reinterpret_cast<v4f*>(&smem[r * 132 + c0 + 4]) = o1;
    }
    __syncthreads();

    // Scatter phase: stream the CSR segment of this 64-node tile.
    // unit = one float4 of one output row; 32 units/row. Lanes 0..31 of a
    // wave share a row (512 B contiguous NT store, rowlist load broadcasts);
    // LDS read is 2 full 512 B rows per wave -> conflict-free.
    int endn = node0 + 64; if (endn > N_NODES) endn = N_NODES;
    const int beg = off[node0];
    const int end = off[endn];
    for (long u = (long)beg * 32 + tid; u < (long)end * 32; u += 256) {
        unsigned pk = rowlist[u >> 5];
        int c  = (int)(u & 31);
        long e = pk >> 6;
        int lr = pk & 63;
        v4f v = *reinterpret_cast<const v4f*>(&smem[lr * 132 + c * 4]);
        __builtin_nontemporal_store(v, &y4[e * 32 + c]);
    }
}

extern "C" void kernel_launch(void* const* d_in, const int* in_sizes, int n_in,
                              void* d_out, int out_size, void* d_ws, size_t ws_size,
                              hipStream_t stream) {
    const float* x   = (const float*)d_in[0];
    const int*   idx = (const int*)d_in[1];
    const float* W1  = (const float*)d_in[2];
    const float* b1  = (const float*)d_in[3];
    const float* W2  = (const float*)d_in[4];
    const float* b2  = (const float*)d_in[5];
    float* y = (float*)d_out;

    // workspace layout (~3.9 MB of the >=25 MB workspace)
    float*    W1f     = (float*)d_ws;                    // 16384 floats
    int*      count   = (int*)(W1f + C * C);             // 50000
    int*      off     = count + N_NODES;                 // 50001
    int*      cursor  = off + N_NODES + 1;               // 50000
    unsigned* rowlist = (unsigned*)(cursor + N_NODES);   // 800000

    hipLaunchKernelGGL(prep_kernel, dim3(196), dim3(256), 0, stream, W1, W1f, count);
    hipLaunchKernelGGL(hist_kernel, dim3((N_ROWS + 255) / 256), dim3(256), 0, stream,
                       idx, count);
    hipLaunchKernelGGL(scan_kernel, dim3(1), dim3(1024), 0, stream, count, off, cursor);
    hipLaunchKernelGGL(build_kernel, dim3((N_ROWS + 255) / 256), dim3(256), 0, stream,
                       idx, cursor, rowlist);
    hipLaunchKernelGGL(node_scatter_kernel, dim3((N_NODES + 63) / 64), dim3(256), 0,
                       stream, x, W1f, b1, W2, b2, off, rowlist, (v4f*)y);
}

// Round 4
// 590.713 us; speedup vs baseline: 1.1506x; 1.1506x over previous
//
#include <hip/hip_runtime.h>

typedef float v4f __attribute__((ext_vector_type(4)));
typedef unsigned int v4u __attribute__((ext_vector_type(4)));

#define N_NODES 50000
#define N_ROWS  800000
#define C 128

// float -> bf16 (round to nearest even), returned in low 16 bits
__device__ inline unsigned bf16rne(float f) {
    unsigned b = __float_as_uint(f);
    return (b + 0x7FFFu + ((b >> 16) & 1u)) >> 16;
}
__device__ inline float blo(unsigned w) { return __uint_as_float(w << 16); }
__device__ inline float bhi(unsigned w) { return __uint_as_float(w & 0xFFFF0000u); }

// W1f = W1[0:128,:] + W1[128:256,:]  (concat([g,g]) @ W1 == g @ W1f)
__global__ __launch_bounds__(256) void prep_w1f(const float* __restrict__ W1,
                                                float* __restrict__ W1f) {
    int i = blockIdx.x * 256 + threadIdx.x;
    if (i < C * C) W1f[i] = W1[i] + W1[C * C + i];
}

// Per-node fused: z = relu(x @ W1f + b1) @ W2 + b2, stored as bf16 (RNE).
// Block = 256 threads, tile = 64 rows x 128 cols. Thread (rg,cg) computes
// rows {rg,+16,+32,+48} x cols [8cg, 8cg+8). LDS [64][132] (pad => conflict-
// free column reads) reused x-tile -> h-tile, barrier-separated.
__global__ __launch_bounds__(256) void node_kernel(
    const float* __restrict__ x, const float* __restrict__ W1f,
    const float* __restrict__ b1, const float* __restrict__ W2,
    const float* __restrict__ b2, unsigned short* __restrict__ zb)
{
    __shared__ float smem[64 * 132];
    const int tid = threadIdx.x;
    const int cg  = tid & 15;
    const int rg  = tid >> 4;
    const int c0  = cg * 8;
    const int node0 = blockIdx.x * 64;

    // stage x tile (coalesced float4, non-temporal: x is read exactly once)
    {
        int r  = tid >> 5;            // 0..7
        int c4 = (tid & 31) * 4;      // 0..124
        #pragma unroll
        for (int it = 0; it < 8; ++it, r += 8) {
            int gr = node0 + r;
            if (gr >= N_NODES) gr = N_NODES - 1;   // clamp: safe read, write guarded later
            v4f v = __builtin_nontemporal_load(
                reinterpret_cast<const v4f*>(&x[(long)gr * C + c4]));
            *reinterpret_cast<v4f*>(&smem[r * 132 + c4]) = v;
        }
    }
    __syncthreads();

    float acc[4][8];
    #pragma unroll
    for (int m = 0; m < 4; ++m)
        #pragma unroll
        for (int j = 0; j < 8; ++j) acc[m][j] = 0.f;

    // GEMM1: h = x @ W1f
    #pragma unroll 4
    for (int k = 0; k < C; ++k) {
        v4f w0 = *reinterpret_cast<const v4f*>(&W1f[k * C + c0]);
        v4f w1 = *reinterpret_cast<const v4f*>(&W1f[k * C + c0 + 4]);
        #pragma unroll
        for (int m = 0; m < 4; ++m) {
            float xv = smem[(rg + 16 * m) * 132 + k];
            acc[m][0] += xv * w0.x; acc[m][1] += xv * w0.y;
            acc[m][2] += xv * w0.z; acc[m][3] += xv * w0.w;
            acc[m][4] += xv * w1.x; acc[m][5] += xv * w1.y;
            acc[m][6] += xv * w1.z; acc[m][7] += xv * w1.w;
        }
    }

    float bb[8];
    #pragma unroll
    for (int j = 0; j < 8; ++j) bb[j] = b1[c0 + j];

    __syncthreads();   // all x reads complete before overwriting buffer with h
    #pragma unroll
    for (int m = 0; m < 4; ++m) {
        int r = rg + 16 * m;
        v4f h0, h1;
        h0.x = acc[m][0] + bb[0]; h0.y = acc[m][1] + bb[1];
        h0.z = acc[m][2] + bb[2]; h0.w = acc[m][3] + bb[3];
        h1.x = acc[m][4] + bb[4]; h1.y = acc[m][5] + bb[5];
        h1.z = acc[m][6] + bb[6]; h1.w = acc[m][7] + bb[7];
        h0.x = h0.x > 0.f ? h0.x : 0.f; h0.y = h0.y > 0.f ? h0.y : 0.f;
        h0.z = h0.z > 0.f ? h0.z : 0.f; h0.w = h0.w > 0.f ? h0.w : 0.f;
        h1.x = h1.x > 0.f ? h1.x : 0.f; h1.y = h1.y > 0.f ? h1.y : 0.f;
        h1.z = h1.z > 0.f ? h1.z : 0.f; h1.w = h1.w > 0.f ? h1.w : 0.f;
        *reinterpret_cast<v4f*>(&smem[r * 132 + c0])     = h0;
        *reinterpret_cast<v4f*>(&smem[r * 132 + c0 + 4]) = h1;
    }
    __syncthreads();

    #pragma unroll
    for (int m = 0; m < 4; ++m)
        #pragma unroll
        for (int j = 0; j < 8; ++j) acc[m][j] = 0.f;

    // GEMM2: z = h @ W2
    #pragma unroll 4
    for (int k = 0; k < C; ++k) {
        v4f w0 = *reinterpret_cast<const v4f*>(&W2[k * C + c0]);
        v4f w1 = *reinterpret_cast<const v4f*>(&W2[k * C + c0 + 4]);
        #pragma unroll
        for (int m = 0; m < 4; ++m) {
            float hv = smem[(rg + 16 * m) * 132 + k];
            acc[m][0] += hv * w0.x; acc[m][1] += hv * w0.y;
            acc[m][2] += hv * w0.z; acc[m][3] += hv * w0.w;
            acc[m][4] += hv * w1.x; acc[m][5] += hv * w1.y;
            acc[m][6] += hv * w1.z; acc[m][7] += hv * w1.w;
        }
    }

    #pragma unroll
    for (int j = 0; j < 8; ++j) bb[j] = b2[c0 + j];

    #pragma unroll
    for (int m = 0; m < 4; ++m) {
        int gr = node0 + rg + 16 * m;
        if (gr < N_NODES) {
            // pack 8 outputs -> 4x u32 (bf16x2), one 16 B store.
            // wave writes 4 rows x 256 B contiguous segments -> coalesced.
            v4u w;
            w.x = bf16rne(acc[m][0] + bb[0]) | (bf16rne(acc[m][1] + bb[1]) << 16);
            w.y = bf16rne(acc[m][2] + bb[2]) | (bf16rne(acc[m][3] + bb[3]) << 16);
            w.z = bf16rne(acc[m][4] + bb[4]) | (bf16rne(acc[m][5] + bb[5]) << 16);
            w.w = bf16rne(acc[m][6] + bb[6]) | (bf16rne(acc[m][7] + bb[7]) << 16);
            // plain (cached) store: z re-read 16x by gather, keep L2/L3 resident
            *reinterpret_cast<v4u*>(&zb[(long)gr * C + c0]) = w;
        }
    }
}

// y[e] = fp32(zb[idx[e]])  — unit = 16 B of bf16 z (8 vals) -> 32 B of y.
// 16 units per row; lanes of a 16-lane group share a row (256 B contiguous
// z-read, idx broadcast). 4 independent units per thread for MLP depth.
// NT y-stores (410 MB stream must not evict the 12.8 MB z from L2/L3);
// NT idx loads (read-once stream). The two 16 B stores per unit interleave
// at 32 B stride; back-to-back in the same wave they fill complete L2 lines
// (NT = evict-hint, still write-combines in L2).
__global__ __launch_bounds__(256) void gather_kernel(
    const v4u* __restrict__ zq, const int* __restrict__ idx,
    v4f* __restrict__ y4)
{
    const long base = (long)blockIdx.x * 1024 + threadIdx.x;

    int e[4], c[4], n[4];
    #pragma unroll
    for (int it = 0; it < 4; ++it) {
        long u = base + it * 256;
        e[it] = (int)(u >> 4);
        c[it] = (int)(u & 15);
        n[it] = __builtin_nontemporal_load(&idx[e[it]]);
    }

    v4u w[4];
    #pragma unroll
    for (int it = 0; it < 4; ++it)
        w[it] = zq[(long)n[it] * 16 + c[it]];

    #pragma unroll
    for (int it = 0; it < 4; ++it) {
        v4f a, b;
        a.x = blo(w[it].x); a.y = bhi(w[it].x);
        a.z = blo(w[it].y); a.w = bhi(w[it].y);
        b.x = blo(w[it].z); b.y = bhi(w[it].z);
        b.z = blo(w[it].w); b.w = bhi(w[it].w);
        long yo = (long)e[it] * 32 + c[it] * 2;
        __builtin_nontemporal_store(a, &y4[yo]);
        __builtin_nontemporal_store(b, &y4[yo + 1]);
    }
}

extern "C" void kernel_launch(void* const* d_in, const int* in_sizes, int n_in,
                              void* d_out, int out_size, void* d_ws, size_t ws_size,
                              hipStream_t stream) {
    const float* x   = (const float*)d_in[0];
    const int*   idx = (const int*)d_in[1];
    const float* W1  = (const float*)d_in[2];
    const float* b1  = (const float*)d_in[3];
    const float* W2  = (const float*)d_in[4];
    const float* b2  = (const float*)d_in[5];
    float* y = (float*)d_out;

    unsigned short* zb = (unsigned short*)d_ws;        // 50000*128 bf16 = 12.8 MB
    float* W1f = (float*)(zb + (size_t)N_NODES * C);   // +64 KB

    hipLaunchKernelGGL(prep_w1f, dim3(64), dim3(256), 0, stream, W1, W1f);
    hipLaunchKernelGGL(node_kernel, dim3((N_NODES + 63) / 64), dim3(256), 0, stream,
                       x, W1f, b1, W2, b2, zb);
    // N_ROWS*16 units / 1024 units-per-block = 12500 blocks
    hipLaunchKernelGGL(gather_kernel, dim3((N_ROWS * 16) / 1024), dim3(256), 0, stream,
                       (const v4u*)zb, idx, (v4f*)y);
}